// Round 9
// baseline (617.893 us; speedup 1.0000x reference)
//
#include <hip/hip_runtime.h>

#define SS 4096
#define NROWS 16384   // B*S

typedef __bf16 bf16;
typedef __attribute__((ext_vector_type(8))) __bf16 bf16x8;
typedef __attribute__((ext_vector_type(4))) float f32x4;

__device__ __forceinline__ float b2f(bf16 v) { return (float)v; }
__device__ __forceinline__ bf16  f2b(float f) { return (bf16)f; }

// ---------------------------------------------------------------- prep
__global__ __launch_bounds__(256) void prep_kernel(
    const float* __restrict__ x, float* __restrict__ pos,
    bf16* __restrict__ featb, float* __restrict__ sq)
{
    int row = blockIdx.x, t = threadIdx.x;
    const float* xr = x + (size_t)row * 259;
    float v = xr[3 + t];
    featb[(size_t)row * 256 + t] = f2b(v);
    if (t < 3) pos[row * 3 + t] = xr[t];
    float s = v * v;
#pragma unroll
    for (int o = 32; o >= 1; o >>= 1) s += __shfl_xor(s, o);
    __shared__ float wsum[4];
    if ((t & 63) == 0) wsum[t >> 6] = s;
    __syncthreads();
    if (t == 0) sq[row] = wsum[0] + wsum[1] + wsum[2] + wsum[3];
}

// ---------------------------------------------------------------- weight prep, stage 1
__global__ void wprep1_kernel(const float* __restrict__ wqw, const float* __restrict__ wkw,
                              const float* __restrict__ g1w, const float* __restrict__ fc2w,
                              const float* __restrict__ g2w,
                              float* __restrict__ M1q, float* __restrict__ M1k,
                              bf16* __restrict__ fc2T, bf16* __restrict__ g2T)
{
    int job = blockIdx.y, i = blockIdx.x, j = threadIdx.x;
    if (job < 2) {
        const float* A = job ? wkw : wqw;
        float acc = 0.f;
#pragma unroll 4
        for (int d = 0; d < 256; d++) acc += A[i * 256 + d] * g1w[d * 256 + j];
        (job ? M1k : M1q)[i * 256 + j] = acc;
    } else {
        const float* S = (job == 2) ? fc2w : g2w;
        bf16* D = (job == 2) ? fc2T : g2T;
        D[i * 256 + j] = f2b(S[j * 256 + i]);
    }
}

// ---------------------------------------------------------------- weight prep, stage 2
__global__ void wprep2_kernel(const float* __restrict__ fc1w, const float* __restrict__ fc1b,
                              const float* __restrict__ M1q, const float* __restrict__ M1k,
                              const float* __restrict__ wvw, const float* __restrict__ g1b,
                              bf16* __restrict__ WqT, bf16* __restrict__ WkT, bf16* __restrict__ WvT,
                              float* __restrict__ qbias, float* __restrict__ kbias, float* __restrict__ vbias)
{
    int job = blockIdx.y, n = blockIdx.x, k = threadIdx.x;
    if (job < 3) {
        const float* M = (job == 0) ? M1q : (job == 1) ? M1k : wvw;
        float acc = 0.f;
#pragma unroll 4
        for (int d = 0; d < 256; d++) acc += fc1w[k * 256 + d] * M[d * 256 + n];
        bf16* D = (job == 0) ? WqT : (job == 1) ? WkT : WvT;
        D[n * 256 + k] = f2b(acc);
    } else if (n == 0) {
        float aq = 0.f, ak = 0.f, av = 0.f;
#pragma unroll 4
        for (int d = 0; d < 256; d++) {
            float f = fc1b[d];
            aq += f * M1q[d * 256 + k];
            ak += f * M1k[d * 256 + k];
            av += f * wvw[d * 256 + k];
        }
        qbias[k] = aq + g1b[k];
        kbias[k] = ak;
        vbias[k] = av;
    }
}

// ---------------------------------------------------------------- q/k/v GEMM (one launch, z-indexed)
__global__ __launch_bounds__(256, 3) void qkv_gemm_kernel(
    const bf16* __restrict__ A,
    const bf16* __restrict__ BT0, const bf16* __restrict__ BT1, const bf16* __restrict__ BT2,
    const float* __restrict__ bias0, const float* __restrict__ bias1, const float* __restrict__ bias2,
    bf16* __restrict__ O0, bf16* __restrict__ O1, bf16* __restrict__ O2)
{
    int z = blockIdx.z;
    const bf16* BT = (z == 0) ? BT0 : (z == 1) ? BT1 : BT2;
    const float* bias = (z == 0) ? bias0 : (z == 1) ? bias1 : bias2;
    bf16* Ob = (z == 0) ? O0 : (z == 1) ? O1 : O2;

    int t = threadIdx.x, lane = t & 63, w = t >> 6, quad = lane >> 4, l15 = lane & 15;
    int row0 = blockIdx.y * 128 + (w >> 1) * 64;
    int col0 = blockIdx.x * 128 + (w & 1) * 64;
    f32x4 acc[4][4];
#pragma unroll
    for (int i = 0; i < 4; i++)
#pragma unroll
        for (int j = 0; j < 4; j++) acc[i][j] = (f32x4){0.f, 0.f, 0.f, 0.f};
    const bf16* Ap = A + (size_t)(row0 + l15) * 256 + quad * 8;
    const bf16* Bp = BT + (size_t)(col0 + l15) * 256 + quad * 8;
#pragma unroll
    for (int k = 0; k < 8; k++) {
        bf16x8 af[4], bfr[4];
#pragma unroll
        for (int mt = 0; mt < 4; mt++) af[mt] = *(const bf16x8*)(Ap + mt * 16 * 256 + k * 32);
#pragma unroll
        for (int nt = 0; nt < 4; nt++) bfr[nt] = *(const bf16x8*)(Bp + nt * 16 * 256 + k * 32);
#pragma unroll
        for (int mt = 0; mt < 4; mt++)
#pragma unroll
            for (int nt = 0; nt < 4; nt++)
                acc[mt][nt] = __builtin_amdgcn_mfma_f32_16x16x32_bf16(af[mt], bfr[nt], acc[mt][nt], 0, 0, 0);
    }
#pragma unroll
    for (int mt = 0; mt < 4; mt++)
#pragma unroll
        for (int nt = 0; nt < 4; nt++) {
            int rb = row0 + mt * 16 + quad * 4;
            int c = col0 + nt * 16 + l15;
            float bv = bias[c];
#pragma unroll
            for (int reg = 0; reg < 4; reg++)
                Ob[(size_t)(rb + reg) * 256 + c] = f2b(acc[mt][nt][reg] + bv);
        }
}

// ---------------------------------------------------------------- final GEMM (fp32 out + residual)
__global__ __launch_bounds__(256, 3) void gemm_out_kernel(
    const bf16* __restrict__ A, const bf16* __restrict__ BT,
    const float* __restrict__ bias, float* __restrict__ Of, const float* __restrict__ resid)
{
    int t = threadIdx.x, lane = t & 63, w = t >> 6, quad = lane >> 4, l15 = lane & 15;
    int row0 = blockIdx.y * 128 + (w >> 1) * 64;
    int col0 = blockIdx.x * 128 + (w & 1) * 64;
    f32x4 acc[4][4];
#pragma unroll
    for (int i = 0; i < 4; i++)
#pragma unroll
        for (int j = 0; j < 4; j++) acc[i][j] = (f32x4){0.f, 0.f, 0.f, 0.f};
    const bf16* Ap = A + (size_t)(row0 + l15) * 256 + quad * 8;
    const bf16* Bp = BT + (size_t)(col0 + l15) * 256 + quad * 8;
#pragma unroll
    for (int k = 0; k < 8; k++) {
        bf16x8 af[4], bfr[4];
#pragma unroll
        for (int mt = 0; mt < 4; mt++) af[mt] = *(const bf16x8*)(Ap + mt * 16 * 256 + k * 32);
#pragma unroll
        for (int nt = 0; nt < 4; nt++) bfr[nt] = *(const bf16x8*)(Bp + nt * 16 * 256 + k * 32);
#pragma unroll
        for (int mt = 0; mt < 4; mt++)
#pragma unroll
            for (int nt = 0; nt < 4; nt++)
                acc[mt][nt] = __builtin_amdgcn_mfma_f32_16x16x32_bf16(af[mt], bfr[nt], acc[mt][nt], 0, 0, 0);
    }
#pragma unroll
    for (int mt = 0; mt < 4; mt++)
#pragma unroll
        for (int nt = 0; nt < 4; nt++) {
            int rb = row0 + mt * 16 + quad * 4;
            int c = col0 + nt * 16 + l15;
            float bv = bias[c];
#pragma unroll
            for (int reg = 0; reg < 4; reg++) {
                int r = rb + reg;
                Of[(size_t)r * 256 + c] = acc[mt][nt][reg] + bv + resid[(size_t)r * 259 + 3 + c];
            }
        }
}

// ---------------------------------------------------------------- fused gram + top-16 KNN
// ROUND-7 VERSION (measured 230 us) — round-8's "pipeline" reorder regressed to
// 342 us because compute(t+1) before pops forces s_waitcnt vmcnt(0) (MFMA needs
// the loads) BEFORE the pop chains: the load stall moved into the critical path.
// 512 threads (8 waves), 32 rows x 4096 cols, grid (128,4). LDS 32x256 fp32,
// unit-swizzled (conflicts = 0). __launch_bounds__(512,4): NOT 8 (round-5 spill).
__global__ __launch_bounds__(512, 4) void knn_kernel(
    const bf16* __restrict__ featb, const float* __restrict__ sq, int* __restrict__ idxout)
{
    __shared__ __align__(16) float lds[32 * 256];   // 32768 B
    int t = threadIdx.x, lane = t & 63, w = t >> 6, quad = lane >> 4, l15 = lane & 15;
    int b = blockIdx.y;
    int row0 = blockIdx.x * 32;
    const bf16* F = featb + (size_t)b * SS * 256;
    const float* sqb = sq + b * SS;

    unsigned int Lv[4]; int Li[4];
#pragma unroll
    for (int i = 0; i < 4; i++) { Lv[i] = 0xFFFFFFFFu; Li[i] = 0; }

    const bf16* Ap0 = F + (size_t)(row0 + l15) * 256 + quad * 8;
    const bf16* Ap1 = Ap0 + 16 * 256;

    for (int tile = 0; tile < 16; tile++) {
        int c0 = tile * 256;
        f32x4 acc[2][2];
#pragma unroll
        for (int i = 0; i < 2; i++)
#pragma unroll
            for (int j = 0; j < 2; j++) acc[i][j] = (f32x4){0.f, 0.f, 0.f, 0.f};
        const bf16* Bp = F + (size_t)(c0 + w * 32 + l15) * 256 + quad * 8;
#pragma unroll
        for (int k = 0; k < 8; k++) {
            bf16x8 a0 = *(const bf16x8*)(Ap0 + k * 32);
            bf16x8 a1 = *(const bf16x8*)(Ap1 + k * 32);
            bf16x8 b0 = *(const bf16x8*)(Bp + k * 32);
            bf16x8 b1 = *(const bf16x8*)(Bp + 16 * 256 + k * 32);
            acc[0][0] = __builtin_amdgcn_mfma_f32_16x16x32_bf16(a0, b0, acc[0][0], 0, 0, 0);
            acc[0][1] = __builtin_amdgcn_mfma_f32_16x16x32_bf16(a0, b1, acc[0][1], 0, 0, 0);
            acc[1][0] = __builtin_amdgcn_mfma_f32_16x16x32_bf16(a1, b0, acc[1][0], 0, 0, 0);
            acc[1][1] = __builtin_amdgcn_mfma_f32_16x16x32_bf16(a1, b1, acc[1][1], 0, 0, 0);
        }
        __syncthreads();   // previous tile's selection reads done
#pragma unroll
        for (int nt = 0; nt < 2; nt++) {
            int colL = w * 32 + nt * 16 + l15;
            float sqc = sqb[c0 + colL];
#pragma unroll
            for (int mt = 0; mt < 2; mt++) {
#pragma unroll
                for (int reg = 0; reg < 4; reg++) {
                    int rowL = mt * 16 + quad * 4 + reg;
                    int addr = rowL * 256 + ((((colL >> 2) ^ (rowL & 7)) << 2) | (colL & 3));
                    lds[addr] = fmaf(-2.0f, acc[mt][nt][reg], sqc);
                }
            }
        }
        __syncthreads();
        // selection: wave w owns rows w*4 .. w*4+3
#pragma unroll 1
        for (int r = 0; r < 4; r++) {
            int rowL = w * 4 + r;
            int s = rowL & 7;
            f32x4 dvv = *(const f32x4*)&lds[rowL * 256 + 4 * lane];  // cols ((lane^s)<<2)|j
            unsigned int Lv_r = Lv[r]; int Li_r = Li[r];
            unsigned int T = __shfl(Lv_r, 15);
            unsigned int kk[4];
#pragma unroll
            for (int j = 0; j < 4; j++) {
                unsigned int bits = __float_as_uint(dvv[j]);
                kk[j] = bits ^ ((unsigned int)(((int)bits) >> 31) | 0x80000000u);
            }
#pragma unroll 1
            for (int j = 0; j < 4; j++) {
                unsigned long long mask = __ballot(kk[j] < T);
                while (mask) {
                    int l = __ffsll(mask) - 1;
                    mask &= mask - 1;
                    unsigned int cv = __shfl(kk[j], l);
                    if (cv < T) {
                        int ci = c0 + (((l ^ s) << 2) | j);
                        bool qual = (lane < 16) && (cv < Lv_r);
                        unsigned long long m2 = __ballot(qual);
                        int pos = __ffsll(m2) - 1;
                        unsigned int sv = __shfl_up(Lv_r, 1);
                        int si = __shfl_up(Li_r, 1);
                        Lv_r = (lane == pos) ? cv : ((lane > pos) ? sv : Lv_r);
                        Li_r = (lane == pos) ? ci : ((lane > pos) ? si : Li_r);
                        T = __shfl(Lv_r, 15);
                    }
                }
            }
            Lv[r] = Lv_r; Li[r] = Li_r;
        }
    }
    // lanes 0..15 hold the 16 nearest for each owned row
#pragma unroll 1
    for (int r = 0; r < 4; r++) {
        if (lane < 16)
            idxout[((size_t)b * SS + row0 + w * 4 + r) * 16 + lane] = Li[r];
    }
}

// ---------------------------------------------------------------- fused edge MLP
// ROUND 9 change: 4 groups/block (was 8) -> LDS 33.8 KB, grid 4096 blocks
// -> 4 blocks/CU x 4 waves = 16 waves/CU (was 2 blocks/CU = 8 waves/CU).
__global__ __launch_bounds__(256, 4) void edge_kernel(
    const bf16* __restrict__ qb, const bf16* __restrict__ kg1, const bf16* __restrict__ vf,
    const bf16* __restrict__ g2T, const float* __restrict__ g2b,
    const int* __restrict__ idx, bf16* __restrict__ res)
{
    __shared__ __align__(16) bf16 e1[4 * 16 * 264];
    __shared__ int nbrs[4][16];
    int t = threadIdx.x, lane = t & 63, w = t >> 6, quad = lane >> 4, l15 = lane & 15;
    int G0 = blockIdx.x * 4;
    int bb = G0 & ~(SS - 1);
    if (t < 64) {
        int g = t >> 4, r = t & 15;
        nbrs[g][r] = bb + idx[(size_t)(G0 + g) * 16 + r];
    }
    bf16x8 bg[4][8];
#pragma unroll
    for (int nt = 0; nt < 4; nt++)
#pragma unroll
        for (int k = 0; k < 8; k++)
            bg[nt][k] = *(const bf16x8*)(g2T + (size_t)(w * 64 + nt * 16 + l15) * 256 + k * 32 + quad * 8);
    __syncthreads();
#pragma unroll 4
    for (int i = 0; i < 8; i++) {
        int f = i * 256 + t;
        int c8 = f & 31, r = (f >> 5) & 15, g = f >> 9;
        int nbr = nbrs[g][r];
        bf16x8 qv = *(const bf16x8*)(qb + (size_t)(G0 + g) * 256 + c8 * 8);
        bf16x8 kv = *(const bf16x8*)(kg1 + (size_t)nbr * 256 + c8 * 8);
        bf16x8 e;
#pragma unroll
        for (int j = 0; j < 8; j++) {
            float d = b2f(qv[j]) - b2f(kv[j]);
            e[j] = f2b(fmaxf(d, 0.0f));
        }
        *(bf16x8*)(&e1[(g * 16 + r) * 264 + c8 * 8]) = e;
    }
    __syncthreads();
#pragma unroll 1
    for (int g = 0; g < 4; g++) {
        f32x4 acc[4];
#pragma unroll
        for (int nt = 0; nt < 4; nt++) acc[nt] = (f32x4){0.f, 0.f, 0.f, 0.f};
#pragma unroll
        for (int k = 0; k < 8; k++) {
            bf16x8 a = *(const bf16x8*)(&e1[(g * 16 + l15) * 264 + k * 32 + quad * 8]);
#pragma unroll
            for (int nt = 0; nt < 4; nt++)
                acc[nt] = __builtin_amdgcn_mfma_f32_16x16x32_bf16(a, bg[nt][k], acc[nt], 0, 0, 0);
        }
        int grow = G0 + g;
#pragma unroll
        for (int nt = 0; nt < 4; nt++) {
            int col = w * 64 + nt * 16 + l15;
            float b2v = g2b[col];
            float lg[4], p[4];
#pragma unroll
            for (int reg = 0; reg < 4; reg++) lg[reg] = (acc[nt][reg] + b2v) * 0.0625f;
            float mx = fmaxf(fmaxf(lg[0], lg[1]), fmaxf(lg[2], lg[3]));
            mx = fmaxf(mx, __shfl_xor(mx, 16));
            mx = fmaxf(mx, __shfl_xor(mx, 32));
            float ps = 0.f;
#pragma unroll
            for (int reg = 0; reg < 4; reg++) { p[reg] = __expf(lg[reg] - mx); ps += p[reg]; }
            ps += __shfl_xor(ps, 16);
            ps += __shfl_xor(ps, 32);
            float inv = __builtin_amdgcn_rcpf(ps);
            float rs = 0.f;
#pragma unroll
            for (int reg = 0; reg < 4; reg++) {
                int nbr = nbrs[g][quad * 4 + reg];
                rs += p[reg] * b2f(vf[(size_t)nbr * 256 + col]);
            }
            rs *= inv;
            rs += __shfl_xor(rs, 16);
            rs += __shfl_xor(rs, 32);
            if (quad == 0) res[(size_t)grow * 256 + col] = f2b(rs);
        }
    }
}

// ---------------------------------------------------------------- launcher
extern "C" void kernel_launch(void* const* d_in, const int* in_sizes, int n_in,
                              void* d_out, int out_size, void* d_ws, size_t ws_size,
                              hipStream_t stream)
{
    (void)in_sizes; (void)n_in; (void)out_size; (void)ws_size;
    const float* x    = (const float*)d_in[0];
    const float* fc1w = (const float*)d_in[1];
    const float* fc1b = (const float*)d_in[2];
    const float* fc2w = (const float*)d_in[3];
    const float* fc2b = (const float*)d_in[4];
    const float* wqw  = (const float*)d_in[5];
    const float* wkw  = (const float*)d_in[6];
    const float* wvw  = (const float*)d_in[7];
    const float* g1w  = (const float*)d_in[8];
    const float* g1b  = (const float*)d_in[9];
    const float* g2w  = (const float*)d_in[10];
    const float* g2b  = (const float*)d_in[11];

    float* pos_out = (float*)d_out;
    float* out     = (float*)d_out + (size_t)NROWS * 3;

    char* ws = (char*)d_ws;
    size_t off = 0;
    auto alloc = [&](size_t bytes) { void* p = ws + off; off += (bytes + 255) & ~(size_t)255; return p; };
    bf16* featb = (bf16*)alloc((size_t)NROWS * 256 * 2);
    bf16* qbuf  = (bf16*)alloc((size_t)NROWS * 256 * 2);
    bf16* kg    = (bf16*)alloc((size_t)NROWS * 256 * 2);
    bf16* vf    = (bf16*)alloc((size_t)NROWS * 256 * 2);
    bf16* res   = (bf16*)alloc((size_t)NROWS * 256 * 2);
    float* sq   = (float*)alloc((size_t)NROWS * 4);
    int* idx    = (int*)alloc((size_t)NROWS * 16 * 4);
    float* M1q  = (float*)alloc(65536 * 4);
    float* M1k  = (float*)alloc(65536 * 4);
    bf16* WqT   = (bf16*)alloc(65536 * 2);
    bf16* WkT   = (bf16*)alloc(65536 * 2);
    bf16* WvT   = (bf16*)alloc(65536 * 2);
    bf16* fc2T  = (bf16*)alloc(65536 * 2);
    bf16* g2T   = (bf16*)alloc(65536 * 2);
    float* qbias = (float*)alloc(256 * 4);
    float* kbias = (float*)alloc(256 * 4);
    float* vbias = (float*)alloc(256 * 4);

    prep_kernel<<<NROWS, 256, 0, stream>>>(x, pos_out, featb, sq);
    wprep1_kernel<<<dim3(256, 4), 256, 0, stream>>>(wqw, wkw, g1w, fc2w, g2w, M1q, M1k, fc2T, g2T);
    wprep2_kernel<<<dim3(256, 4), 256, 0, stream>>>(fc1w, fc1b, M1q, M1k, wvw, g1b,
                                                    WqT, WkT, WvT, qbias, kbias, vbias);

    qkv_gemm_kernel<<<dim3(2, NROWS / 128, 3), 256, 0, stream>>>(
        featb, WqT, WkT, WvT, qbias, kbias, vbias, qbuf, kg, vf);

    knn_kernel<<<dim3(SS / 32, 4), 512, 0, stream>>>(featb, sq, idx);

    edge_kernel<<<NROWS / 4, 256, 0, stream>>>(qbuf, kg, vf, g2T, g2b, idx, res);

    gemm_out_kernel<<<dim3(2, NROWS / 128), 256, 0, stream>>>(res, fc2T, fc2b, out, x);
}

// Round 10
// 584.330 us; speedup vs baseline: 1.0574x; 1.0574x over previous
//
#include <hip/hip_runtime.h>

#define SS 4096
#define NROWS 16384   // B*S

typedef __bf16 bf16;
typedef __attribute__((ext_vector_type(8))) __bf16 bf16x8;
typedef __attribute__((ext_vector_type(4))) float f32x4;

__device__ __forceinline__ float b2f(bf16 v) { return (float)v; }
__device__ __forceinline__ bf16  f2b(float f) { return (bf16)f; }

// ---------------------------------------------------------------- prep
__global__ __launch_bounds__(256) void prep_kernel(
    const float* __restrict__ x, float* __restrict__ pos,
    bf16* __restrict__ featb, float* __restrict__ sq)
{
    int row = blockIdx.x, t = threadIdx.x;
    const float* xr = x + (size_t)row * 259;
    float v = xr[3 + t];
    featb[(size_t)row * 256 + t] = f2b(v);
    if (t < 3) pos[row * 3 + t] = xr[t];
    float s = v * v;
#pragma unroll
    for (int o = 32; o >= 1; o >>= 1) s += __shfl_xor(s, o);
    __shared__ float wsum[4];
    if ((t & 63) == 0) wsum[t >> 6] = s;
    __syncthreads();
    if (t == 0) sq[row] = wsum[0] + wsum[1] + wsum[2] + wsum[3];
}

// ---------------------------------------------------------------- weight prep, stage 1
__global__ void wprep1_kernel(const float* __restrict__ wqw, const float* __restrict__ wkw,
                              const float* __restrict__ g1w, const float* __restrict__ fc2w,
                              const float* __restrict__ g2w,
                              float* __restrict__ M1q, float* __restrict__ M1k,
                              bf16* __restrict__ fc2T, bf16* __restrict__ g2T)
{
    int job = blockIdx.y, i = blockIdx.x, j = threadIdx.x;
    if (job < 2) {
        const float* A = job ? wkw : wqw;
        float acc = 0.f;
#pragma unroll 4
        for (int d = 0; d < 256; d++) acc += A[i * 256 + d] * g1w[d * 256 + j];
        (job ? M1k : M1q)[i * 256 + j] = acc;
    } else {
        const float* S = (job == 2) ? fc2w : g2w;
        bf16* D = (job == 2) ? fc2T : g2T;
        D[i * 256 + j] = f2b(S[j * 256 + i]);
    }
}

// ---------------------------------------------------------------- weight prep, stage 2
__global__ void wprep2_kernel(const float* __restrict__ fc1w, const float* __restrict__ fc1b,
                              const float* __restrict__ M1q, const float* __restrict__ M1k,
                              const float* __restrict__ wvw, const float* __restrict__ g1b,
                              bf16* __restrict__ WqT, bf16* __restrict__ WkT, bf16* __restrict__ WvT,
                              float* __restrict__ qbias, float* __restrict__ kbias, float* __restrict__ vbias)
{
    int job = blockIdx.y, n = blockIdx.x, k = threadIdx.x;
    if (job < 3) {
        const float* M = (job == 0) ? M1q : (job == 1) ? M1k : wvw;
        float acc = 0.f;
#pragma unroll 4
        for (int d = 0; d < 256; d++) acc += fc1w[k * 256 + d] * M[d * 256 + n];
        bf16* D = (job == 0) ? WqT : (job == 1) ? WkT : WvT;
        D[n * 256 + k] = f2b(acc);
    } else if (n == 0) {
        float aq = 0.f, ak = 0.f, av = 0.f;
#pragma unroll 4
        for (int d = 0; d < 256; d++) {
            float f = fc1b[d];
            aq += f * M1q[d * 256 + k];
            ak += f * M1k[d * 256 + k];
            av += f * wvw[d * 256 + k];
        }
        qbias[k] = aq + g1b[k];
        kbias[k] = ak;
        vbias[k] = av;
    }
}

// ---------------------------------------------------------------- q/k/v GEMM (one launch, z-indexed)
__global__ __launch_bounds__(256, 3) void qkv_gemm_kernel(
    const bf16* __restrict__ A,
    const bf16* __restrict__ BT0, const bf16* __restrict__ BT1, const bf16* __restrict__ BT2,
    const float* __restrict__ bias0, const float* __restrict__ bias1, const float* __restrict__ bias2,
    bf16* __restrict__ O0, bf16* __restrict__ O1, bf16* __restrict__ O2)
{
    int z = blockIdx.z;
    const bf16* BT = (z == 0) ? BT0 : (z == 1) ? BT1 : BT2;
    const float* bias = (z == 0) ? bias0 : (z == 1) ? bias1 : bias2;
    bf16* Ob = (z == 0) ? O0 : (z == 1) ? O1 : O2;

    int t = threadIdx.x, lane = t & 63, w = t >> 6, quad = lane >> 4, l15 = lane & 15;
    int row0 = blockIdx.y * 128 + (w >> 1) * 64;
    int col0 = blockIdx.x * 128 + (w & 1) * 64;
    f32x4 acc[4][4];
#pragma unroll
    for (int i = 0; i < 4; i++)
#pragma unroll
        for (int j = 0; j < 4; j++) acc[i][j] = (f32x4){0.f, 0.f, 0.f, 0.f};
    const bf16* Ap = A + (size_t)(row0 + l15) * 256 + quad * 8;
    const bf16* Bp = BT + (size_t)(col0 + l15) * 256 + quad * 8;
#pragma unroll
    for (int k = 0; k < 8; k++) {
        bf16x8 af[4], bfr[4];
#pragma unroll
        for (int mt = 0; mt < 4; mt++) af[mt] = *(const bf16x8*)(Ap + mt * 16 * 256 + k * 32);
#pragma unroll
        for (int nt = 0; nt < 4; nt++) bfr[nt] = *(const bf16x8*)(Bp + nt * 16 * 256 + k * 32);
#pragma unroll
        for (int mt = 0; mt < 4; mt++)
#pragma unroll
            for (int nt = 0; nt < 4; nt++)
                acc[mt][nt] = __builtin_amdgcn_mfma_f32_16x16x32_bf16(af[mt], bfr[nt], acc[mt][nt], 0, 0, 0);
    }
#pragma unroll
    for (int mt = 0; mt < 4; mt++)
#pragma unroll
        for (int nt = 0; nt < 4; nt++) {
            int rb = row0 + mt * 16 + quad * 4;
            int c = col0 + nt * 16 + l15;
            float bv = bias[c];
#pragma unroll
            for (int reg = 0; reg < 4; reg++)
                Ob[(size_t)(rb + reg) * 256 + c] = f2b(acc[mt][nt][reg] + bv);
        }
}

// ---------------------------------------------------------------- final GEMM (fp32 out + residual)
__global__ __launch_bounds__(256, 3) void gemm_out_kernel(
    const bf16* __restrict__ A, const bf16* __restrict__ BT,
    const float* __restrict__ bias, float* __restrict__ Of, const float* __restrict__ resid)
{
    int t = threadIdx.x, lane = t & 63, w = t >> 6, quad = lane >> 4, l15 = lane & 15;
    int row0 = blockIdx.y * 128 + (w >> 1) * 64;
    int col0 = blockIdx.x * 128 + (w & 1) * 64;
    f32x4 acc[4][4];
#pragma unroll
    for (int i = 0; i < 4; i++)
#pragma unroll
        for (int j = 0; j < 4; j++) acc[i][j] = (f32x4){0.f, 0.f, 0.f, 0.f};
    const bf16* Ap = A + (size_t)(row0 + l15) * 256 + quad * 8;
    const bf16* Bp = BT + (size_t)(col0 + l15) * 256 + quad * 8;
#pragma unroll
    for (int k = 0; k < 8; k++) {
        bf16x8 af[4], bfr[4];
#pragma unroll
        for (int mt = 0; mt < 4; mt++) af[mt] = *(const bf16x8*)(Ap + mt * 16 * 256 + k * 32);
#pragma unroll
        for (int nt = 0; nt < 4; nt++) bfr[nt] = *(const bf16x8*)(Bp + nt * 16 * 256 + k * 32);
#pragma unroll
        for (int mt = 0; mt < 4; mt++)
#pragma unroll
            for (int nt = 0; nt < 4; nt++)
                acc[mt][nt] = __builtin_amdgcn_mfma_f32_16x16x32_bf16(af[mt], bfr[nt], acc[mt][nt], 0, 0, 0);
    }
#pragma unroll
    for (int mt = 0; mt < 4; mt++)
#pragma unroll
        for (int nt = 0; nt < 4; nt++) {
            int rb = row0 + mt * 16 + quad * 4;
            int c = col0 + nt * 16 + l15;
            float bv = bias[c];
#pragma unroll
            for (int reg = 0; reg < 4; reg++) {
                int r = rb + reg;
                Of[(size_t)r * 256 + c] = acc[mt][nt][reg] + bv + resid[(size_t)r * 259 + 3 + c];
            }
        }
}

// ---------------------------------------------------------------- fused gram + top-16 KNN
// ROUND 10: 16 rows x 4096 cols per block, grid (256,4) = 1024 blocks = 4 blocks/CU.
// Round 7's 32-row version was GRID-limited to 2 blocks/CU (512 blocks) = 50% occ cap;
// VGPR=64 allows 8 waves/SIMD and LDS 16 KB allows 4+ blocks/CU, so row-split doubles
// residency WITHOUT duplicating selection state (unlike round-6's col-split: per-row
// scan work is unchanged, no merge pass). Selection: sorted top-16 across lanes 0..15
// (sortable-u32), per-j ballots, shuffle-shift inserts; LDS unit-swizzled, conflicts=0.
// __launch_bounds__(512,4): NOT 8 (round-5 spill lesson).
__global__ __launch_bounds__(512, 4) void knn_kernel(
    const bf16* __restrict__ featb, const float* __restrict__ sq, int* __restrict__ idxout)
{
    __shared__ __align__(16) float lds[16 * 256];   // 16384 B
    int t = threadIdx.x, lane = t & 63, w = t >> 6, quad = lane >> 4, l15 = lane & 15;
    int b = blockIdx.y;
    int row0 = blockIdx.x * 16;
    const bf16* F = featb + (size_t)b * SS * 256;
    const float* sqb = sq + b * SS;

    unsigned int Lv[2]; int Li[2];
#pragma unroll
    for (int i = 0; i < 2; i++) { Lv[i] = 0xFFFFFFFFu; Li[i] = 0; }

    const bf16* Ap0 = F + (size_t)(row0 + l15) * 256 + quad * 8;   // 16 A rows, L1-resident

    for (int tile = 0; tile < 16; tile++) {
        int c0 = tile * 256;
        f32x4 acc[2];
#pragma unroll
        for (int i = 0; i < 2; i++) acc[i] = (f32x4){0.f, 0.f, 0.f, 0.f};
        const bf16* Bp = F + (size_t)(c0 + w * 32 + l15) * 256 + quad * 8;
#pragma unroll
        for (int k = 0; k < 8; k++) {
            bf16x8 a0 = *(const bf16x8*)(Ap0 + k * 32);
            bf16x8 b0 = *(const bf16x8*)(Bp + k * 32);
            bf16x8 b1 = *(const bf16x8*)(Bp + 16 * 256 + k * 32);
            acc[0] = __builtin_amdgcn_mfma_f32_16x16x32_bf16(a0, b0, acc[0], 0, 0, 0);
            acc[1] = __builtin_amdgcn_mfma_f32_16x16x32_bf16(a0, b1, acc[1], 0, 0, 0);
        }
        __syncthreads();   // previous tile's selection reads done
#pragma unroll
        for (int nt = 0; nt < 2; nt++) {
            int colL = w * 32 + nt * 16 + l15;
            float sqc = sqb[c0 + colL];
#pragma unroll
            for (int reg = 0; reg < 4; reg++) {
                int rowL = quad * 4 + reg;
                int addr = rowL * 256 + ((((colL >> 2) ^ (rowL & 7)) << 2) | (colL & 3));
                lds[addr] = fmaf(-2.0f, acc[nt][reg], sqc);
            }
        }
        __syncthreads();
        // selection: wave w owns rows w*2 .. w*2+1
#pragma unroll 1
        for (int r = 0; r < 2; r++) {
            int rowL = w * 2 + r;
            int s = rowL & 7;
            f32x4 dvv = *(const f32x4*)&lds[rowL * 256 + 4 * lane];  // cols ((lane^s)<<2)|j
            unsigned int Lv_r = Lv[r]; int Li_r = Li[r];
            unsigned int T = __shfl(Lv_r, 15);
            unsigned int kk[4];
#pragma unroll
            for (int j = 0; j < 4; j++) {
                unsigned int bits = __float_as_uint(dvv[j]);
                kk[j] = bits ^ ((unsigned int)(((int)bits) >> 31) | 0x80000000u);
            }
#pragma unroll 1
            for (int j = 0; j < 4; j++) {
                unsigned long long mask = __ballot(kk[j] < T);
                while (mask) {
                    int l = __ffsll(mask) - 1;
                    mask &= mask - 1;
                    unsigned int cv = __shfl(kk[j], l);
                    if (cv < T) {
                        int ci = c0 + (((l ^ s) << 2) | j);
                        bool qual = (lane < 16) && (cv < Lv_r);
                        unsigned long long m2 = __ballot(qual);
                        int pos = __ffsll(m2) - 1;
                        unsigned int sv = __shfl_up(Lv_r, 1);
                        int si = __shfl_up(Li_r, 1);
                        Lv_r = (lane == pos) ? cv : ((lane > pos) ? sv : Lv_r);
                        Li_r = (lane == pos) ? ci : ((lane > pos) ? si : Li_r);
                        T = __shfl(Lv_r, 15);
                    }
                }
            }
            Lv[r] = Lv_r; Li[r] = Li_r;
        }
    }
    // lanes 0..15 hold the 16 nearest for each owned row
#pragma unroll 1
    for (int r = 0; r < 2; r++) {
        if (lane < 16)
            idxout[((size_t)b * SS + row0 + w * 2 + r) * 16 + lane] = Li[r];
    }
}

// ---------------------------------------------------------------- fused edge MLP
// ROUND-7 VERSION (8 groups/block, launch_bounds(256,2)). Round-9's 4-group
// variant with (256,4) regressed ~120 us: the 128-VGPR cap spilled bg[4][8]
// (the 128-reg g2T fragment cache) — every k-loop reloaded it from scratch.
__global__ __launch_bounds__(256, 2) void edge_kernel(
    const bf16* __restrict__ qb, const bf16* __restrict__ kg1, const bf16* __restrict__ vf,
    const bf16* __restrict__ g2T, const float* __restrict__ g2b,
    const int* __restrict__ idx, bf16* __restrict__ res)
{
    __shared__ __align__(16) bf16 e1[8 * 16 * 264];
    __shared__ int nbrs[8][16];
    int t = threadIdx.x, lane = t & 63, w = t >> 6, quad = lane >> 4, l15 = lane & 15;
    int G0 = blockIdx.x * 8;
    int bb = G0 & ~(SS - 1);
    if (t < 128) {
        int g = t >> 4, r = t & 15;
        nbrs[g][r] = bb + idx[(size_t)(G0 + g) * 16 + r];
    }
    bf16x8 bg[4][8];
#pragma unroll
    for (int nt = 0; nt < 4; nt++)
#pragma unroll
        for (int k = 0; k < 8; k++)
            bg[nt][k] = *(const bf16x8*)(g2T + (size_t)(w * 64 + nt * 16 + l15) * 256 + k * 32 + quad * 8);
    __syncthreads();
#pragma unroll 4
    for (int i = 0; i < 16; i++) {
        int f = i * 256 + t;
        int c8 = f & 31, r = (f >> 5) & 15, g = f >> 9;
        int nbr = nbrs[g][r];
        bf16x8 qv = *(const bf16x8*)(qb + (size_t)(G0 + g) * 256 + c8 * 8);
        bf16x8 kv = *(const bf16x8*)(kg1 + (size_t)nbr * 256 + c8 * 8);
        bf16x8 e;
#pragma unroll
        for (int j = 0; j < 8; j++) {
            float d = b2f(qv[j]) - b2f(kv[j]);
            e[j] = f2b(fmaxf(d, 0.0f));
        }
        *(bf16x8*)(&e1[(g * 16 + r) * 264 + c8 * 8]) = e;
    }
    __syncthreads();
#pragma unroll 1
    for (int g = 0; g < 8; g++) {
        f32x4 acc[4];
#pragma unroll
        for (int nt = 0; nt < 4; nt++) acc[nt] = (f32x4){0.f, 0.f, 0.f, 0.f};
#pragma unroll
        for (int k = 0; k < 8; k++) {
            bf16x8 a = *(const bf16x8*)(&e1[(g * 16 + l15) * 264 + k * 32 + quad * 8]);
#pragma unroll
            for (int nt = 0; nt < 4; nt++)
                acc[nt] = __builtin_amdgcn_mfma_f32_16x16x32_bf16(a, bg[nt][k], acc[nt], 0, 0, 0);
        }
        int grow = G0 + g;
#pragma unroll
        for (int nt = 0; nt < 4; nt++) {
            int col = w * 64 + nt * 16 + l15;
            float b2v = g2b[col];
            float lg[4], p[4];
#pragma unroll
            for (int reg = 0; reg < 4; reg++) lg[reg] = (acc[nt][reg] + b2v) * 0.0625f;
            float mx = fmaxf(fmaxf(lg[0], lg[1]), fmaxf(lg[2], lg[3]));
            mx = fmaxf(mx, __shfl_xor(mx, 16));
            mx = fmaxf(mx, __shfl_xor(mx, 32));
            float ps = 0.f;
#pragma unroll
            for (int reg = 0; reg < 4; reg++) { p[reg] = __expf(lg[reg] - mx); ps += p[reg]; }
            ps += __shfl_xor(ps, 16);
            ps += __shfl_xor(ps, 32);
            float inv = __builtin_amdgcn_rcpf(ps);
            float rs = 0.f;
#pragma unroll
            for (int reg = 0; reg < 4; reg++) {
                int nbr = nbrs[g][quad * 4 + reg];
                rs += p[reg] * b2f(vf[(size_t)nbr * 256 + col]);
            }
            rs *= inv;
            rs += __shfl_xor(rs, 16);
            rs += __shfl_xor(rs, 32);
            if (quad == 0) res[(size_t)grow * 256 + col] = f2b(rs);
        }
    }
}

// ---------------------------------------------------------------- launcher
extern "C" void kernel_launch(void* const* d_in, const int* in_sizes, int n_in,
                              void* d_out, int out_size, void* d_ws, size_t ws_size,
                              hipStream_t stream)
{
    (void)in_sizes; (void)n_in; (void)out_size; (void)ws_size;
    const float* x    = (const float*)d_in[0];
    const float* fc1w = (const float*)d_in[1];
    const float* fc1b = (const float*)d_in[2];
    const float* fc2w = (const float*)d_in[3];
    const float* fc2b = (const float*)d_in[4];
    const float* wqw  = (const float*)d_in[5];
    const float* wkw  = (const float*)d_in[6];
    const float* wvw  = (const float*)d_in[7];
    const float* g1w  = (const float*)d_in[8];
    const float* g1b  = (const float*)d_in[9];
    const float* g2w  = (const float*)d_in[10];
    const float* g2b  = (const float*)d_in[11];

    float* pos_out = (float*)d_out;
    float* out     = (float*)d_out + (size_t)NROWS * 3;

    char* ws = (char*)d_ws;
    size_t off = 0;
    auto alloc = [&](size_t bytes) { void* p = ws + off; off += (bytes + 255) & ~(size_t)255; return p; };
    bf16* featb = (bf16*)alloc((size_t)NROWS * 256 * 2);
    bf16* qbuf  = (bf16*)alloc((size_t)NROWS * 256 * 2);
    bf16* kg    = (bf16*)alloc((size_t)NROWS * 256 * 2);
    bf16* vf    = (bf16*)alloc((size_t)NROWS * 256 * 2);
    bf16* res   = (bf16*)alloc((size_t)NROWS * 256 * 2);
    float* sq   = (float*)alloc((size_t)NROWS * 4);
    int* idx    = (int*)alloc((size_t)NROWS * 16 * 4);
    float* M1q  = (float*)alloc(65536 * 4);
    float* M1k  = (float*)alloc(65536 * 4);
    bf16* WqT   = (bf16*)alloc(65536 * 2);
    bf16* WkT   = (bf16*)alloc(65536 * 2);
    bf16* WvT   = (bf16*)alloc(65536 * 2);
    bf16* fc2T  = (bf16*)alloc(65536 * 2);
    bf16* g2T   = (bf16*)alloc(65536 * 2);
    float* qbias = (float*)alloc(256 * 4);
    float* kbias = (float*)alloc(256 * 4);
    float* vbias = (float*)alloc(256 * 4);

    prep_kernel<<<NROWS, 256, 0, stream>>>(x, pos_out, featb, sq);
    wprep1_kernel<<<dim3(256, 4), 256, 0, stream>>>(wqw, wkw, g1w, fc2w, g2w, M1q, M1k, fc2T, g2T);
    wprep2_kernel<<<dim3(256, 4), 256, 0, stream>>>(fc1w, fc1b, M1q, M1k, wvw, g1b,
                                                    WqT, WkT, WvT, qbias, kbias, vbias);

    qkv_gemm_kernel<<<dim3(2, NROWS / 128, 3), 256, 0, stream>>>(
        featb, WqT, WkT, WvT, qbias, kbias, vbias, qbuf, kg, vf);

    knn_kernel<<<dim3(SS / 16, 4), 512, 0, stream>>>(featb, sq, idx);

    edge_kernel<<<NROWS / 8, 256, 0, stream>>>(qbuf, kg, vf, g2T, g2b, idx, res);

    gemm_out_kernel<<<dim3(2, NROWS / 128), 256, 0, stream>>>(res, fc2T, fc2b, out, x);
}

// Round 11
// 482.156 us; speedup vs baseline: 1.2815x; 1.2119x over previous
//
#include <hip/hip_runtime.h>

#define SS 4096
#define NROWS 16384   // B*S

typedef __bf16 bf16;
typedef __attribute__((ext_vector_type(8))) __bf16 bf16x8;
typedef __attribute__((ext_vector_type(4))) float f32x4;

__device__ __forceinline__ float b2f(bf16 v) { return (float)v; }
__device__ __forceinline__ bf16  f2b(float f) { return (bf16)f; }

// ---------------------------------------------------------------- prep
__global__ __launch_bounds__(256) void prep_kernel(
    const float* __restrict__ x, float* __restrict__ pos,
    bf16* __restrict__ featb, float* __restrict__ sq)
{
    int row = blockIdx.x, t = threadIdx.x;
    const float* xr = x + (size_t)row * 259;
    float v = xr[3 + t];
    featb[(size_t)row * 256 + t] = f2b(v);
    if (t < 3) pos[row * 3 + t] = xr[t];
    float s = v * v;
#pragma unroll
    for (int o = 32; o >= 1; o >>= 1) s += __shfl_xor(s, o);
    __shared__ float wsum[4];
    if ((t & 63) == 0) wsum[t >> 6] = s;
    __syncthreads();
    if (t == 0) sq[row] = wsum[0] + wsum[1] + wsum[2] + wsum[3];
}

// ---------------------------------------------------------------- weight prep, stage 1
__global__ void wprep1_kernel(const float* __restrict__ wqw, const float* __restrict__ wkw,
                              const float* __restrict__ g1w, const float* __restrict__ fc2w,
                              const float* __restrict__ g2w,
                              float* __restrict__ M1q, float* __restrict__ M1k,
                              bf16* __restrict__ fc2T, bf16* __restrict__ g2T)
{
    int job = blockIdx.y, i = blockIdx.x, j = threadIdx.x;
    if (job < 2) {
        const float* A = job ? wkw : wqw;
        float acc = 0.f;
#pragma unroll 4
        for (int d = 0; d < 256; d++) acc += A[i * 256 + d] * g1w[d * 256 + j];
        (job ? M1k : M1q)[i * 256 + j] = acc;
    } else {
        const float* S = (job == 2) ? fc2w : g2w;
        bf16* D = (job == 2) ? fc2T : g2T;
        D[i * 256 + j] = f2b(S[j * 256 + i]);
    }
}

// ---------------------------------------------------------------- weight prep, stage 2
__global__ void wprep2_kernel(const float* __restrict__ fc1w, const float* __restrict__ fc1b,
                              const float* __restrict__ M1q, const float* __restrict__ M1k,
                              const float* __restrict__ wvw, const float* __restrict__ g1b,
                              bf16* __restrict__ WqT, bf16* __restrict__ WkT, bf16* __restrict__ WvT,
                              float* __restrict__ qbias, float* __restrict__ kbias, float* __restrict__ vbias)
{
    int job = blockIdx.y, n = blockIdx.x, k = threadIdx.x;
    if (job < 3) {
        const float* M = (job == 0) ? M1q : (job == 1) ? M1k : wvw;
        float acc = 0.f;
#pragma unroll 4
        for (int d = 0; d < 256; d++) acc += fc1w[k * 256 + d] * M[d * 256 + n];
        bf16* D = (job == 0) ? WqT : (job == 1) ? WkT : WvT;
        D[n * 256 + k] = f2b(acc);
    } else if (n == 0) {
        float aq = 0.f, ak = 0.f, av = 0.f;
#pragma unroll 4
        for (int d = 0; d < 256; d++) {
            float f = fc1b[d];
            aq += f * M1q[d * 256 + k];
            ak += f * M1k[d * 256 + k];
            av += f * wvw[d * 256 + k];
        }
        qbias[k] = aq + g1b[k];
        kbias[k] = ak;
        vbias[k] = av;
    }
}

// ---------------------------------------------------------------- q/k/v GEMM (one launch, z-indexed)
__global__ __launch_bounds__(256, 3) void qkv_gemm_kernel(
    const bf16* __restrict__ A,
    const bf16* __restrict__ BT0, const bf16* __restrict__ BT1, const bf16* __restrict__ BT2,
    const float* __restrict__ bias0, const float* __restrict__ bias1, const float* __restrict__ bias2,
    bf16* __restrict__ O0, bf16* __restrict__ O1, bf16* __restrict__ O2)
{
    int z = blockIdx.z;
    const bf16* BT = (z == 0) ? BT0 : (z == 1) ? BT1 : BT2;
    const float* bias = (z == 0) ? bias0 : (z == 1) ? bias1 : bias2;
    bf16* Ob = (z == 0) ? O0 : (z == 1) ? O1 : O2;

    int t = threadIdx.x, lane = t & 63, w = t >> 6, quad = lane >> 4, l15 = lane & 15;
    int row0 = blockIdx.y * 128 + (w >> 1) * 64;
    int col0 = blockIdx.x * 128 + (w & 1) * 64;
    f32x4 acc[4][4];
#pragma unroll
    for (int i = 0; i < 4; i++)
#pragma unroll
        for (int j = 0; j < 4; j++) acc[i][j] = (f32x4){0.f, 0.f, 0.f, 0.f};
    const bf16* Ap = A + (size_t)(row0 + l15) * 256 + quad * 8;
    const bf16* Bp = BT + (size_t)(col0 + l15) * 256 + quad * 8;
#pragma unroll
    for (int k = 0; k < 8; k++) {
        bf16x8 af[4], bfr[4];
#pragma unroll
        for (int mt = 0; mt < 4; mt++) af[mt] = *(const bf16x8*)(Ap + mt * 16 * 256 + k * 32);
#pragma unroll
        for (int nt = 0; nt < 4; nt++) bfr[nt] = *(const bf16x8*)(Bp + nt * 16 * 256 + k * 32);
#pragma unroll
        for (int mt = 0; mt < 4; mt++)
#pragma unroll
            for (int nt = 0; nt < 4; nt++)
                acc[mt][nt] = __builtin_amdgcn_mfma_f32_16x16x32_bf16(af[mt], bfr[nt], acc[mt][nt], 0, 0, 0);
    }
#pragma unroll
    for (int mt = 0; mt < 4; mt++)
#pragma unroll
        for (int nt = 0; nt < 4; nt++) {
            int rb = row0 + mt * 16 + quad * 4;
            int c = col0 + nt * 16 + l15;
            float bv = bias[c];
#pragma unroll
            for (int reg = 0; reg < 4; reg++)
                Ob[(size_t)(rb + reg) * 256 + c] = f2b(acc[mt][nt][reg] + bv);
        }
}

// ---------------------------------------------------------------- final GEMM (fp32 out + residual)
__global__ __launch_bounds__(256, 3) void gemm_out_kernel(
    const bf16* __restrict__ A, const bf16* __restrict__ BT,
    const float* __restrict__ bias, float* __restrict__ Of, const float* __restrict__ resid)
{
    int t = threadIdx.x, lane = t & 63, w = t >> 6, quad = lane >> 4, l15 = lane & 15;
    int row0 = blockIdx.y * 128 + (w >> 1) * 64;
    int col0 = blockIdx.x * 128 + (w & 1) * 64;
    f32x4 acc[4][4];
#pragma unroll
    for (int i = 0; i < 4; i++)
#pragma unroll
        for (int j = 0; j < 4; j++) acc[i][j] = (f32x4){0.f, 0.f, 0.f, 0.f};
    const bf16* Ap = A + (size_t)(row0 + l15) * 256 + quad * 8;
    const bf16* Bp = BT + (size_t)(col0 + l15) * 256 + quad * 8;
#pragma unroll
    for (int k = 0; k < 8; k++) {
        bf16x8 af[4], bfr[4];
#pragma unroll
        for (int mt = 0; mt < 4; mt++) af[mt] = *(const bf16x8*)(Ap + mt * 16 * 256 + k * 32);
#pragma unroll
        for (int nt = 0; nt < 4; nt++) bfr[nt] = *(const bf16x8*)(Bp + nt * 16 * 256 + k * 32);
#pragma unroll
        for (int mt = 0; mt < 4; mt++)
#pragma unroll
            for (int nt = 0; nt < 4; nt++)
                acc[mt][nt] = __builtin_amdgcn_mfma_f32_16x16x32_bf16(af[mt], bfr[nt], acc[mt][nt], 0, 0, 0);
    }
#pragma unroll
    for (int mt = 0; mt < 4; mt++)
#pragma unroll
        for (int nt = 0; nt < 4; nt++) {
            int rb = row0 + mt * 16 + quad * 4;
            int c = col0 + nt * 16 + l15;
            float bv = bias[c];
#pragma unroll
            for (int reg = 0; reg < 4; reg++) {
                int r = rb + reg;
                Of[(size_t)r * 256 + c] = acc[mt][nt][reg] + bv + resid[(size_t)r * 259 + 3 + c];
            }
        }
}

// ---------------------------------------------------------------- fused gram + top-16 KNN
// FROZEN at the ROUND-7 config (measured 230 us — best). Attempts that regressed:
// col-split (r5/r6), compute-before-pops pipeline (r8), 16-row split (r10: 316 us,
// occupancy unchanged at ~44% — the cap is not grid/LDS/VGPR-structural).
// 512 threads (8 waves), 32 rows x 4096 cols, grid (128,4). LDS 32x256 fp32,
// unit-swizzled (conflicts = 0). __launch_bounds__(512,4): NOT 8 (round-5 spill).
__global__ __launch_bounds__(512, 4) void knn_kernel(
    const bf16* __restrict__ featb, const float* __restrict__ sq, int* __restrict__ idxout)
{
    __shared__ __align__(16) float lds[32 * 256];   // 32768 B
    int t = threadIdx.x, lane = t & 63, w = t >> 6, quad = lane >> 4, l15 = lane & 15;
    int b = blockIdx.y;
    int row0 = blockIdx.x * 32;
    const bf16* F = featb + (size_t)b * SS * 256;
    const float* sqb = sq + b * SS;

    unsigned int Lv[4]; int Li[4];
#pragma unroll
    for (int i = 0; i < 4; i++) { Lv[i] = 0xFFFFFFFFu; Li[i] = 0; }

    const bf16* Ap0 = F + (size_t)(row0 + l15) * 256 + quad * 8;
    const bf16* Ap1 = Ap0 + 16 * 256;

    for (int tile = 0; tile < 16; tile++) {
        int c0 = tile * 256;
        f32x4 acc[2][2];
#pragma unroll
        for (int i = 0; i < 2; i++)
#pragma unroll
            for (int j = 0; j < 2; j++) acc[i][j] = (f32x4){0.f, 0.f, 0.f, 0.f};
        const bf16* Bp = F + (size_t)(c0 + w * 32 + l15) * 256 + quad * 8;
#pragma unroll
        for (int k = 0; k < 8; k++) {
            bf16x8 a0 = *(const bf16x8*)(Ap0 + k * 32);
            bf16x8 a1 = *(const bf16x8*)(Ap1 + k * 32);
            bf16x8 b0 = *(const bf16x8*)(Bp + k * 32);
            bf16x8 b1 = *(const bf16x8*)(Bp + 16 * 256 + k * 32);
            acc[0][0] = __builtin_amdgcn_mfma_f32_16x16x32_bf16(a0, b0, acc[0][0], 0, 0, 0);
            acc[0][1] = __builtin_amdgcn_mfma_f32_16x16x32_bf16(a0, b1, acc[0][1], 0, 0, 0);
            acc[1][0] = __builtin_amdgcn_mfma_f32_16x16x32_bf16(a1, b0, acc[1][0], 0, 0, 0);
            acc[1][1] = __builtin_amdgcn_mfma_f32_16x16x32_bf16(a1, b1, acc[1][1], 0, 0, 0);
        }
        __syncthreads();   // previous tile's selection reads done
#pragma unroll
        for (int nt = 0; nt < 2; nt++) {
            int colL = w * 32 + nt * 16 + l15;
            float sqc = sqb[c0 + colL];
#pragma unroll
            for (int mt = 0; mt < 2; mt++) {
#pragma unroll
                for (int reg = 0; reg < 4; reg++) {
                    int rowL = mt * 16 + quad * 4 + reg;
                    int addr = rowL * 256 + ((((colL >> 2) ^ (rowL & 7)) << 2) | (colL & 3));
                    lds[addr] = fmaf(-2.0f, acc[mt][nt][reg], sqc);
                }
            }
        }
        __syncthreads();
        // selection: wave w owns rows w*4 .. w*4+3
#pragma unroll 1
        for (int r = 0; r < 4; r++) {
            int rowL = w * 4 + r;
            int s = rowL & 7;
            f32x4 dvv = *(const f32x4*)&lds[rowL * 256 + 4 * lane];  // cols ((lane^s)<<2)|j
            unsigned int Lv_r = Lv[r]; int Li_r = Li[r];
            unsigned int T = __shfl(Lv_r, 15);
            unsigned int kk[4];
#pragma unroll
            for (int j = 0; j < 4; j++) {
                unsigned int bits = __float_as_uint(dvv[j]);
                kk[j] = bits ^ ((unsigned int)(((int)bits) >> 31) | 0x80000000u);
            }
#pragma unroll 1
            for (int j = 0; j < 4; j++) {
                unsigned long long mask = __ballot(kk[j] < T);
                while (mask) {
                    int l = __ffsll(mask) - 1;
                    mask &= mask - 1;
                    unsigned int cv = __shfl(kk[j], l);
                    if (cv < T) {
                        int ci = c0 + (((l ^ s) << 2) | j);
                        bool qual = (lane < 16) && (cv < Lv_r);
                        unsigned long long m2 = __ballot(qual);
                        int pos = __ffsll(m2) - 1;
                        unsigned int sv = __shfl_up(Lv_r, 1);
                        int si = __shfl_up(Li_r, 1);
                        Lv_r = (lane == pos) ? cv : ((lane > pos) ? sv : Lv_r);
                        Li_r = (lane == pos) ? ci : ((lane > pos) ? si : Li_r);
                        T = __shfl(Lv_r, 15);
                    }
                }
            }
            Lv[r] = Lv_r; Li[r] = Li_r;
        }
    }
    // lanes 0..15 hold the 16 nearest for each owned row
#pragma unroll 1
    for (int r = 0; r < 4; r++) {
        if (lane < 16)
            idxout[((size_t)b * SS + row0 + w * 4 + r) * 16 + lane] = Li[r];
    }
}

// ---------------------------------------------------------------- fused edge MLP
// ROUND 11: 512 threads (8 waves), still 8 groups/block (LDS 67.6 KB unchanged,
// 2 blocks/CU) but now 16 waves/CU resident (was 8). Each wave owns a 32-col
// slice of g2T -> bg[2][8] = 64 VGPRs (was 128: r9's spill hazard gone).
// MFMA work per wave halves; same total. (512,3): cap 170 VGPR, expect ~120.
__global__ __launch_bounds__(512, 3) void edge_kernel(
    const bf16* __restrict__ qb, const bf16* __restrict__ kg1, const bf16* __restrict__ vf,
    const bf16* __restrict__ g2T, const float* __restrict__ g2b,
    const int* __restrict__ idx, bf16* __restrict__ res)
{
    __shared__ __align__(16) bf16 e1[8 * 16 * 264];
    __shared__ int nbrs[8][16];
    int t = threadIdx.x, lane = t & 63, w = t >> 6, quad = lane >> 4, l15 = lane & 15;
    int G0 = blockIdx.x * 8;
    int bb = G0 & ~(SS - 1);
    if (t < 128) {
        int g = t >> 4, r = t & 15;
        nbrs[g][r] = bb + idx[(size_t)(G0 + g) * 16 + r];
    }
    // per-wave 32-col slice of g2T (cols w*32 .. w*32+31)
    bf16x8 bg[2][8];
#pragma unroll
    for (int nt = 0; nt < 2; nt++)
#pragma unroll
        for (int k = 0; k < 8; k++)
            bg[nt][k] = *(const bf16x8*)(g2T + (size_t)(w * 32 + nt * 16 + l15) * 256 + k * 32 + quad * 8);
    __syncthreads();
    // build E1 (relu(q - kg)) into LDS cooperatively: 4096 bf16x8 chunks / 512 thr
#pragma unroll 4
    for (int i = 0; i < 8; i++) {
        int f = i * 512 + t;
        int c8 = f & 31, r = (f >> 5) & 15, g = f >> 9;
        int nbr = nbrs[g][r];
        bf16x8 qv = *(const bf16x8*)(qb + (size_t)(G0 + g) * 256 + c8 * 8);
        bf16x8 kv = *(const bf16x8*)(kg1 + (size_t)nbr * 256 + c8 * 8);
        bf16x8 e;
#pragma unroll
        for (int j = 0; j < 8; j++) {
            float d = b2f(qv[j]) - b2f(kv[j]);
            e[j] = f2b(fmaxf(d, 0.0f));
        }
        *(bf16x8*)(&e1[(g * 16 + r) * 264 + c8 * 8]) = e;
    }
    __syncthreads();
#pragma unroll 1
    for (int g = 0; g < 8; g++) {
        f32x4 acc[2];
#pragma unroll
        for (int nt = 0; nt < 2; nt++) acc[nt] = (f32x4){0.f, 0.f, 0.f, 0.f};
#pragma unroll
        for (int k = 0; k < 8; k++) {
            bf16x8 a = *(const bf16x8*)(&e1[(g * 16 + l15) * 264 + k * 32 + quad * 8]);
#pragma unroll
            for (int nt = 0; nt < 2; nt++)
                acc[nt] = __builtin_amdgcn_mfma_f32_16x16x32_bf16(a, bg[nt][k], acc[nt], 0, 0, 0);
        }
        int grow = G0 + g;
#pragma unroll
        for (int nt = 0; nt < 2; nt++) {
            int col = w * 32 + nt * 16 + l15;
            float b2v = g2b[col];
            float lg[4], p[4];
#pragma unroll
            for (int reg = 0; reg < 4; reg++) lg[reg] = (acc[nt][reg] + b2v) * 0.0625f;
            float mx = fmaxf(fmaxf(lg[0], lg[1]), fmaxf(lg[2], lg[3]));
            mx = fmaxf(mx, __shfl_xor(mx, 16));
            mx = fmaxf(mx, __shfl_xor(mx, 32));
            float ps = 0.f;
#pragma unroll
            for (int reg = 0; reg < 4; reg++) { p[reg] = __expf(lg[reg] - mx); ps += p[reg]; }
            ps += __shfl_xor(ps, 16);
            ps += __shfl_xor(ps, 32);
            float inv = __builtin_amdgcn_rcpf(ps);
            float rs = 0.f;
#pragma unroll
            for (int reg = 0; reg < 4; reg++) {
                int nbr = nbrs[g][quad * 4 + reg];
                rs += p[reg] * b2f(vf[(size_t)nbr * 256 + col]);
            }
            rs *= inv;
            rs += __shfl_xor(rs, 16);
            rs += __shfl_xor(rs, 32);
            if (quad == 0) res[(size_t)grow * 256 + col] = f2b(rs);
        }
    }
}

// ---------------------------------------------------------------- launcher
extern "C" void kernel_launch(void* const* d_in, const int* in_sizes, int n_in,
                              void* d_out, int out_size, void* d_ws, size_t ws_size,
                              hipStream_t stream)
{
    (void)in_sizes; (void)n_in; (void)out_size; (void)ws_size;
    const float* x    = (const float*)d_in[0];
    const float* fc1w = (const float*)d_in[1];
    const float* fc1b = (const float*)d_in[2];
    const float* fc2w = (const float*)d_in[3];
    const float* fc2b = (const float*)d_in[4];
    const float* wqw  = (const float*)d_in[5];
    const float* wkw  = (const float*)d_in[6];
    const float* wvw  = (const float*)d_in[7];
    const float* g1w  = (const float*)d_in[8];
    const float* g1b  = (const float*)d_in[9];
    const float* g2w  = (const float*)d_in[10];
    const float* g2b  = (const float*)d_in[11];

    float* pos_out = (float*)d_out;
    float* out     = (float*)d_out + (size_t)NROWS * 3;

    char* ws = (char*)d_ws;
    size_t off = 0;
    auto alloc = [&](size_t bytes) { void* p = ws + off; off += (bytes + 255) & ~(size_t)255; return p; };
    bf16* featb = (bf16*)alloc((size_t)NROWS * 256 * 2);
    bf16* qbuf  = (bf16*)alloc((size_t)NROWS * 256 * 2);
    bf16* kg    = (bf16*)alloc((size_t)NROWS * 256 * 2);
    bf16* vf    = (bf16*)alloc((size_t)NROWS * 256 * 2);
    bf16* res   = (bf16*)alloc((size_t)NROWS * 256 * 2);
    float* sq   = (float*)alloc((size_t)NROWS * 4);
    int* idx    = (int*)alloc((size_t)NROWS * 16 * 4);
    float* M1q  = (float*)alloc(65536 * 4);
    float* M1k  = (float*)alloc(65536 * 4);
    bf16* WqT   = (bf16*)alloc(65536 * 2);
    bf16* WkT   = (bf16*)alloc(65536 * 2);
    bf16* WvT   = (bf16*)alloc(65536 * 2);
    bf16* fc2T  = (bf16*)alloc(65536 * 2);
    bf16* g2T   = (bf16*)alloc(65536 * 2);
    float* qbias = (float*)alloc(256 * 4);
    float* kbias = (float*)alloc(256 * 4);
    float* vbias = (float*)alloc(256 * 4);

    prep_kernel<<<NROWS, 256, 0, stream>>>(x, pos_out, featb, sq);
    wprep1_kernel<<<dim3(256, 4), 256, 0, stream>>>(wqw, wkw, g1w, fc2w, g2w, M1q, M1k, fc2T, g2T);
    wprep2_kernel<<<dim3(256, 4), 256, 0, stream>>>(fc1w, fc1b, M1q, M1k, wvw, g1b,
                                                    WqT, WkT, WvT, qbias, kbias, vbias);

    qkv_gemm_kernel<<<dim3(2, NROWS / 128, 3), 256, 0, stream>>>(
        featb, WqT, WkT, WvT, qbias, kbias, vbias, qbuf, kg, vf);

    knn_kernel<<<dim3(SS / 32, 4), 512, 0, stream>>>(featb, sq, idx);

    edge_kernel<<<NROWS / 8, 512, 0, stream>>>(qbuf, kg, vf, g2T, g2b, idx, res);

    gemm_out_kernel<<<dim3(2, NROWS / 128), 256, 0, stream>>>(res, fc2T, fc2b, out, x);
}

// Round 12
// 479.564 us; speedup vs baseline: 1.2884x; 1.0054x over previous
//
#include <hip/hip_runtime.h>

#define SS 4096
#define NROWS 16384   // B*S

typedef __bf16 bf16;
typedef __attribute__((ext_vector_type(8))) __bf16 bf16x8;
typedef __attribute__((ext_vector_type(4))) float f32x4;

__device__ __forceinline__ float b2f(bf16 v) { return (float)v; }
__device__ __forceinline__ bf16  f2b(float f) { return (bf16)f; }

// ---------------------------------------------------------------- prep
__global__ __launch_bounds__(256) void prep_kernel(
    const float* __restrict__ x, float* __restrict__ pos,
    bf16* __restrict__ featb, float* __restrict__ sq)
{
    int row = blockIdx.x, t = threadIdx.x;
    const float* xr = x + (size_t)row * 259;
    float v = xr[3 + t];
    featb[(size_t)row * 256 + t] = f2b(v);
    if (t < 3) pos[row * 3 + t] = xr[t];
    float s = v * v;
#pragma unroll
    for (int o = 32; o >= 1; o >>= 1) s += __shfl_xor(s, o);
    __shared__ float wsum[4];
    if ((t & 63) == 0) wsum[t >> 6] = s;
    __syncthreads();
    if (t == 0) sq[row] = wsum[0] + wsum[1] + wsum[2] + wsum[3];
}

// ---------------------------------------------------------------- weight prep, stage 1
__global__ void wprep1_kernel(const float* __restrict__ wqw, const float* __restrict__ wkw,
                              const float* __restrict__ g1w, const float* __restrict__ fc2w,
                              const float* __restrict__ g2w,
                              float* __restrict__ M1q, float* __restrict__ M1k,
                              bf16* __restrict__ fc2T, bf16* __restrict__ g2T)
{
    int job = blockIdx.y, i = blockIdx.x, j = threadIdx.x;
    if (job < 2) {
        const float* A = job ? wkw : wqw;
        float acc = 0.f;
#pragma unroll 4
        for (int d = 0; d < 256; d++) acc += A[i * 256 + d] * g1w[d * 256 + j];
        (job ? M1k : M1q)[i * 256 + j] = acc;
    } else {
        const float* S = (job == 2) ? fc2w : g2w;
        bf16* D = (job == 2) ? fc2T : g2T;
        D[i * 256 + j] = f2b(S[j * 256 + i]);
    }
}

// ---------------------------------------------------------------- weight prep, stage 2
__global__ void wprep2_kernel(const float* __restrict__ fc1w, const float* __restrict__ fc1b,
                              const float* __restrict__ M1q, const float* __restrict__ M1k,
                              const float* __restrict__ wvw, const float* __restrict__ g1b,
                              bf16* __restrict__ WqT, bf16* __restrict__ WkT, bf16* __restrict__ WvT,
                              float* __restrict__ qbias, float* __restrict__ kbias, float* __restrict__ vbias)
{
    int job = blockIdx.y, n = blockIdx.x, k = threadIdx.x;
    if (job < 3) {
        const float* M = (job == 0) ? M1q : (job == 1) ? M1k : wvw;
        float acc = 0.f;
#pragma unroll 4
        for (int d = 0; d < 256; d++) acc += fc1w[k * 256 + d] * M[d * 256 + n];
        bf16* D = (job == 0) ? WqT : (job == 1) ? WkT : WvT;
        D[n * 256 + k] = f2b(acc);
    } else if (n == 0) {
        float aq = 0.f, ak = 0.f, av = 0.f;
#pragma unroll 4
        for (int d = 0; d < 256; d++) {
            float f = fc1b[d];
            aq += f * M1q[d * 256 + k];
            ak += f * M1k[d * 256 + k];
            av += f * wvw[d * 256 + k];
        }
        qbias[k] = aq + g1b[k];
        kbias[k] = ak;
        vbias[k] = av;
    }
}

// ---------------------------------------------------------------- q/k/v GEMM (one launch, z-indexed)
__global__ __launch_bounds__(256, 3) void qkv_gemm_kernel(
    const bf16* __restrict__ A,
    const bf16* __restrict__ BT0, const bf16* __restrict__ BT1, const bf16* __restrict__ BT2,
    const float* __restrict__ bias0, const float* __restrict__ bias1, const float* __restrict__ bias2,
    bf16* __restrict__ O0, bf16* __restrict__ O1, bf16* __restrict__ O2)
{
    int z = blockIdx.z;
    const bf16* BT = (z == 0) ? BT0 : (z == 1) ? BT1 : BT2;
    const float* bias = (z == 0) ? bias0 : (z == 1) ? bias1 : bias2;
    bf16* Ob = (z == 0) ? O0 : (z == 1) ? O1 : O2;

    int t = threadIdx.x, lane = t & 63, w = t >> 6, quad = lane >> 4, l15 = lane & 15;
    int row0 = blockIdx.y * 128 + (w >> 1) * 64;
    int col0 = blockIdx.x * 128 + (w & 1) * 64;
    f32x4 acc[4][4];
#pragma unroll
    for (int i = 0; i < 4; i++)
#pragma unroll
        for (int j = 0; j < 4; j++) acc[i][j] = (f32x4){0.f, 0.f, 0.f, 0.f};
    const bf16* Ap = A + (size_t)(row0 + l15) * 256 + quad * 8;
    const bf16* Bp = BT + (size_t)(col0 + l15) * 256 + quad * 8;
#pragma unroll
    for (int k = 0; k < 8; k++) {
        bf16x8 af[4], bfr[4];
#pragma unroll
        for (int mt = 0; mt < 4; mt++) af[mt] = *(const bf16x8*)(Ap + mt * 16 * 256 + k * 32);
#pragma unroll
        for (int nt = 0; nt < 4; nt++) bfr[nt] = *(const bf16x8*)(Bp + nt * 16 * 256 + k * 32);
#pragma unroll
        for (int mt = 0; mt < 4; mt++)
#pragma unroll
            for (int nt = 0; nt < 4; nt++)
                acc[mt][nt] = __builtin_amdgcn_mfma_f32_16x16x32_bf16(af[mt], bfr[nt], acc[mt][nt], 0, 0, 0);
    }
#pragma unroll
    for (int mt = 0; mt < 4; mt++)
#pragma unroll
        for (int nt = 0; nt < 4; nt++) {
            int rb = row0 + mt * 16 + quad * 4;
            int c = col0 + nt * 16 + l15;
            float bv = bias[c];
#pragma unroll
            for (int reg = 0; reg < 4; reg++)
                Ob[(size_t)(rb + reg) * 256 + c] = f2b(acc[mt][nt][reg] + bv);
        }
}

// ---------------------------------------------------------------- final GEMM (fp32 out + residual)
__global__ __launch_bounds__(256, 3) void gemm_out_kernel(
    const bf16* __restrict__ A, const bf16* __restrict__ BT,
    const float* __restrict__ bias, float* __restrict__ Of, const float* __restrict__ resid)
{
    int t = threadIdx.x, lane = t & 63, w = t >> 6, quad = lane >> 4, l15 = lane & 15;
    int row0 = blockIdx.y * 128 + (w >> 1) * 64;
    int col0 = blockIdx.x * 128 + (w & 1) * 64;
    f32x4 acc[4][4];
#pragma unroll
    for (int i = 0; i < 4; i++)
#pragma unroll
        for (int j = 0; j < 4; j++) acc[i][j] = (f32x4){0.f, 0.f, 0.f, 0.f};
    const bf16* Ap = A + (size_t)(row0 + l15) * 256 + quad * 8;
    const bf16* Bp = BT + (size_t)(col0 + l15) * 256 + quad * 8;
#pragma unroll
    for (int k = 0; k < 8; k++) {
        bf16x8 af[4], bfr[4];
#pragma unroll
        for (int mt = 0; mt < 4; mt++) af[mt] = *(const bf16x8*)(Ap + mt * 16 * 256 + k * 32);
#pragma unroll
        for (int nt = 0; nt < 4; nt++) bfr[nt] = *(const bf16x8*)(Bp + nt * 16 * 256 + k * 32);
#pragma unroll
        for (int mt = 0; mt < 4; mt++)
#pragma unroll
            for (int nt = 0; nt < 4; nt++)
                acc[mt][nt] = __builtin_amdgcn_mfma_f32_16x16x32_bf16(af[mt], bfr[nt], acc[mt][nt], 0, 0, 0);
    }
#pragma unroll
    for (int mt = 0; mt < 4; mt++)
#pragma unroll
        for (int nt = 0; nt < 4; nt++) {
            int rb = row0 + mt * 16 + quad * 4;
            int c = col0 + nt * 16 + l15;
            float bv = bias[c];
#pragma unroll
            for (int reg = 0; reg < 4; reg++) {
                int r = rb + reg;
                Of[(size_t)r * 256 + c] = acc[mt][nt][reg] + bv + resid[(size_t)r * 259 + 3 + c];
            }
        }
}

// ---------------------------------------------------------------- fused gram + top-16 KNN
// ROUND-7 structure (best) + ROUND-12 packed keys: the per-row top-16 list now
// holds ONE u32 per lane = (sortable-dist top 20 bits) | (12-bit column).
// Quantization step 2^-11 relative — below the bf16 noise already in the
// distances; ties break deterministically by column. Each pop: shfl(cv) +
// ballot + ONE shfl_up + shfl(T) = 3 DS ops (was 4 with separate Li shuffles),
// and cv<T guarantees lane15 qualifies so pos is always valid.
// 512 threads (8 waves), 32 rows x 4096 cols, grid (128,4). LDS 32x256 fp32,
// unit-swizzled (conflicts = 0). __launch_bounds__(512,4): NOT 8 (round-5 spill).
__global__ __launch_bounds__(512, 4) void knn_kernel(
    const bf16* __restrict__ featb, const float* __restrict__ sq, int* __restrict__ idxout)
{
    __shared__ __align__(16) float lds[32 * 256];   // 32768 B
    int t = threadIdx.x, lane = t & 63, w = t >> 6, quad = lane >> 4, l15 = lane & 15;
    int b = blockIdx.y;
    int row0 = blockIdx.x * 32;
    const bf16* F = featb + (size_t)b * SS * 256;
    const float* sqb = sq + b * SS;

    unsigned int Lv[4];
#pragma unroll
    for (int i = 0; i < 4; i++) Lv[i] = 0xFFFFFFFFu;

    const bf16* Ap0 = F + (size_t)(row0 + l15) * 256 + quad * 8;
    const bf16* Ap1 = Ap0 + 16 * 256;

    for (int tile = 0; tile < 16; tile++) {
        int c0 = tile * 256;
        f32x4 acc[2][2];
#pragma unroll
        for (int i = 0; i < 2; i++)
#pragma unroll
            for (int j = 0; j < 2; j++) acc[i][j] = (f32x4){0.f, 0.f, 0.f, 0.f};
        const bf16* Bp = F + (size_t)(c0 + w * 32 + l15) * 256 + quad * 8;
#pragma unroll
        for (int k = 0; k < 8; k++) {
            bf16x8 a0 = *(const bf16x8*)(Ap0 + k * 32);
            bf16x8 a1 = *(const bf16x8*)(Ap1 + k * 32);
            bf16x8 b0 = *(const bf16x8*)(Bp + k * 32);
            bf16x8 b1 = *(const bf16x8*)(Bp + 16 * 256 + k * 32);
            acc[0][0] = __builtin_amdgcn_mfma_f32_16x16x32_bf16(a0, b0, acc[0][0], 0, 0, 0);
            acc[0][1] = __builtin_amdgcn_mfma_f32_16x16x32_bf16(a0, b1, acc[0][1], 0, 0, 0);
            acc[1][0] = __builtin_amdgcn_mfma_f32_16x16x32_bf16(a1, b0, acc[1][0], 0, 0, 0);
            acc[1][1] = __builtin_amdgcn_mfma_f32_16x16x32_bf16(a1, b1, acc[1][1], 0, 0, 0);
        }
        __syncthreads();   // previous tile's selection reads done
#pragma unroll
        for (int nt = 0; nt < 2; nt++) {
            int colL = w * 32 + nt * 16 + l15;
            float sqc = sqb[c0 + colL];
#pragma unroll
            for (int mt = 0; mt < 2; mt++) {
#pragma unroll
                for (int reg = 0; reg < 4; reg++) {
                    int rowL = mt * 16 + quad * 4 + reg;
                    int addr = rowL * 256 + ((((colL >> 2) ^ (rowL & 7)) << 2) | (colL & 3));
                    lds[addr] = fmaf(-2.0f, acc[mt][nt][reg], sqc);
                }
            }
        }
        __syncthreads();
        // selection: wave w owns rows w*4 .. w*4+3
#pragma unroll 1
        for (int r = 0; r < 4; r++) {
            int rowL = w * 4 + r;
            int s = rowL & 7;
            f32x4 dvv = *(const f32x4*)&lds[rowL * 256 + 4 * lane];  // cols ((lane^s)<<2)|j
            unsigned int Lv_r = Lv[r];
            unsigned int T = __shfl(Lv_r, 15);
            int colbase = c0 + ((lane ^ s) << 2);
            unsigned int kk[4];
#pragma unroll
            for (int j = 0; j < 4; j++) {
                unsigned int bits = __float_as_uint(dvv[j]);
                unsigned int key = bits ^ ((unsigned int)(((int)bits) >> 31) | 0x80000000u);
                kk[j] = (key & 0xFFFFF000u) | (unsigned int)(colbase + j);
            }
#pragma unroll 1
            for (int j = 0; j < 4; j++) {
                unsigned long long mask = __ballot(kk[j] < T);
                while (mask) {
                    int l = __ffsll(mask) - 1;
                    mask &= mask - 1;
                    unsigned int cv = __shfl(kk[j], l);
                    if (cv < T) {
                        // cv < T guarantees lane 15 qualifies -> pos in [0,15]
                        bool qual = (lane < 16) && (cv < Lv_r);
                        unsigned long long m2 = __ballot(qual);
                        int pos = __ffsll(m2) - 1;
                        unsigned int sv = __shfl_up(Lv_r, 1);
                        Lv_r = (lane == pos) ? cv : ((lane > pos) ? sv : Lv_r);
                        T = __shfl(Lv_r, 15);
                    }
                }
            }
            Lv[r] = Lv_r;
        }
    }
    // lanes 0..15 hold the 16 nearest for each owned row; low 12 bits = column
#pragma unroll 1
    for (int r = 0; r < 4; r++) {
        if (lane < 16)
            idxout[((size_t)b * SS + row0 + w * 4 + r) * 16 + lane] = (int)(Lv[r] & 0xFFFu);
    }
}

// ---------------------------------------------------------------- fused edge MLP
// ROUND-11 config (best): 512 threads (8 waves), 8 groups/block, per-wave
// 32-col g2T slice (bg[2][8] = 64 VGPRs), 16 waves/CU.
__global__ __launch_bounds__(512, 3) void edge_kernel(
    const bf16* __restrict__ qb, const bf16* __restrict__ kg1, const bf16* __restrict__ vf,
    const bf16* __restrict__ g2T, const float* __restrict__ g2b,
    const int* __restrict__ idx, bf16* __restrict__ res)
{
    __shared__ __align__(16) bf16 e1[8 * 16 * 264];
    __shared__ int nbrs[8][16];
    int t = threadIdx.x, lane = t & 63, w = t >> 6, quad = lane >> 4, l15 = lane & 15;
    int G0 = blockIdx.x * 8;
    int bb = G0 & ~(SS - 1);
    if (t < 128) {
        int g = t >> 4, r = t & 15;
        nbrs[g][r] = bb + idx[(size_t)(G0 + g) * 16 + r];
    }
    bf16x8 bg[2][8];
#pragma unroll
    for (int nt = 0; nt < 2; nt++)
#pragma unroll
        for (int k = 0; k < 8; k++)
            bg[nt][k] = *(const bf16x8*)(g2T + (size_t)(w * 32 + nt * 16 + l15) * 256 + k * 32 + quad * 8);
    __syncthreads();
#pragma unroll 4
    for (int i = 0; i < 8; i++) {
        int f = i * 512 + t;
        int c8 = f & 31, r = (f >> 5) & 15, g = f >> 9;
        int nbr = nbrs[g][r];
        bf16x8 qv = *(const bf16x8*)(qb + (size_t)(G0 + g) * 256 + c8 * 8);
        bf16x8 kv = *(const bf16x8*)(kg1 + (size_t)nbr * 256 + c8 * 8);
        bf16x8 e;
#pragma unroll
        for (int j = 0; j < 8; j++) {
            float d = b2f(qv[j]) - b2f(kv[j]);
            e[j] = f2b(fmaxf(d, 0.0f));
        }
        *(bf16x8*)(&e1[(g * 16 + r) * 264 + c8 * 8]) = e;
    }
    __syncthreads();
#pragma unroll 1
    for (int g = 0; g < 8; g++) {
        f32x4 acc[2];
#pragma unroll
        for (int nt = 0; nt < 2; nt++) acc[nt] = (f32x4){0.f, 0.f, 0.f, 0.f};
#pragma unroll
        for (int k = 0; k < 8; k++) {
            bf16x8 a = *(const bf16x8*)(&e1[(g * 16 + l15) * 264 + k * 32 + quad * 8]);
#pragma unroll
            for (int nt = 0; nt < 2; nt++)
                acc[nt] = __builtin_amdgcn_mfma_f32_16x16x32_bf16(a, bg[nt][k], acc[nt], 0, 0, 0);
        }
        int grow = G0 + g;
#pragma unroll
        for (int nt = 0; nt < 2; nt++) {
            int col = w * 32 + nt * 16 + l15;
            float b2v = g2b[col];
            float lg[4], p[4];
#pragma unroll
            for (int reg = 0; reg < 4; reg++) lg[reg] = (acc[nt][reg] + b2v) * 0.0625f;
            float mx = fmaxf(fmaxf(lg[0], lg[1]), fmaxf(lg[2], lg[3]));
            mx = fmaxf(mx, __shfl_xor(mx, 16));
            mx = fmaxf(mx, __shfl_xor(mx, 32));
            float ps = 0.f;
#pragma unroll
            for (int reg = 0; reg < 4; reg++) { p[reg] = __expf(lg[reg] - mx); ps += p[reg]; }
            ps += __shfl_xor(ps, 16);
            ps += __shfl_xor(ps, 32);
            float inv = __builtin_amdgcn_rcpf(ps);
            float rs = 0.f;
#pragma unroll
            for (int reg = 0; reg < 4; reg++) {
                int nbr = nbrs[g][quad * 4 + reg];
                rs += p[reg] * b2f(vf[(size_t)nbr * 256 + col]);
            }
            rs *= inv;
            rs += __shfl_xor(rs, 16);
            rs += __shfl_xor(rs, 32);
            if (quad == 0) res[(size_t)grow * 256 + col] = f2b(rs);
        }
    }
}

// ---------------------------------------------------------------- launcher
extern "C" void kernel_launch(void* const* d_in, const int* in_sizes, int n_in,
                              void* d_out, int out_size, void* d_ws, size_t ws_size,
                              hipStream_t stream)
{
    (void)in_sizes; (void)n_in; (void)out_size; (void)ws_size;
    const float* x    = (const float*)d_in[0];
    const float* fc1w = (const float*)d_in[1];
    const float* fc1b = (const float*)d_in[2];
    const float* fc2w = (const float*)d_in[3];
    const float* fc2b = (const float*)d_in[4];
    const float* wqw  = (const float*)d_in[5];
    const float* wkw  = (const float*)d_in[6];
    const float* wvw  = (const float*)d_in[7];
    const float* g1w  = (const float*)d_in[8];
    const float* g1b  = (const float*)d_in[9];
    const float* g2w  = (const float*)d_in[10];
    const float* g2b  = (const float*)d_in[11];

    float* pos_out = (float*)d_out;
    float* out     = (float*)d_out + (size_t)NROWS * 3;

    char* ws = (char*)d_ws;
    size_t off = 0;
    auto alloc = [&](size_t bytes) { void* p = ws + off; off += (bytes + 255) & ~(size_t)255; return p; };
    bf16* featb = (bf16*)alloc((size_t)NROWS * 256 * 2);
    bf16* qbuf  = (bf16*)alloc((size_t)NROWS * 256 * 2);
    bf16* kg    = (bf16*)alloc((size_t)NROWS * 256 * 2);
    bf16* vf    = (bf16*)alloc((size_t)NROWS * 256 * 2);
    bf16* res   = (bf16*)alloc((size_t)NROWS * 256 * 2);
    float* sq   = (float*)alloc((size_t)NROWS * 4);
    int* idx    = (int*)alloc((size_t)NROWS * 16 * 4);
    float* M1q  = (float*)alloc(65536 * 4);
    float* M1k  = (float*)alloc(65536 * 4);
    bf16* WqT   = (bf16*)alloc(65536 * 2);
    bf16* WkT   = (bf16*)alloc(65536 * 2);
    bf16* WvT   = (bf16*)alloc(65536 * 2);
    bf16* fc2T  = (bf16*)alloc(65536 * 2);
    bf16* g2T   = (bf16*)alloc(65536 * 2);
    float* qbias = (float*)alloc(256 * 4);
    float* kbias = (float*)alloc(256 * 4);
    float* vbias = (float*)alloc(256 * 4);

    prep_kernel<<<NROWS, 256, 0, stream>>>(x, pos_out, featb, sq);
    wprep1_kernel<<<dim3(256, 4), 256, 0, stream>>>(wqw, wkw, g1w, fc2w, g2w, M1q, M1k, fc2T, g2T);
    wprep2_kernel<<<dim3(256, 4), 256, 0, stream>>>(fc1w, fc1b, M1q, M1k, wvw, g1b,
                                                    WqT, WkT, WvT, qbias, kbias, vbias);

    qkv_gemm_kernel<<<dim3(2, NROWS / 128, 3), 256, 0, stream>>>(
        featb, WqT, WkT, WvT, qbias, kbias, vbias, qbuf, kg, vf);

    knn_kernel<<<dim3(SS / 32, 4), 512, 0, stream>>>(featb, sq, idx);

    edge_kernel<<<NROWS / 8, 512, 0, stream>>>(qbuf, kg, vf, g2T, g2b, idx, res);

    gemm_out_kernel<<<dim3(2, NROWS / 128), 256, 0, stream>>>(res, fc2T, fc2b, out, x);
}